// Round 3
// baseline (95.798 us; speedup 1.0000x reference)
//
#include <hip/hip_runtime.h>
#include <math.h>

#define QHn 128
#define QWn 128
#define Qn  16384
#define Hn  64
#define Wn  64
#define Cn  64
#define Bn  4
#define HIDn 256
#define OUTn 1728   // C*9*3
#define EPSf 1e-6f
// pw scratch layout: [c][p][28] floats -> idx = c*112 + p*28 + (tap*3+o)
#define PW_TOTAL (Cn * 4 * 28)   // 7168 floats

// Reference-faithful coordinate math (fp32, same op order/rounding as jnp).
__device__ __forceinline__ void coord_math(const float* __restrict__ coord,
                                           const float* __restrict__ cell,
                                           int b, int q,
                                           int& iy, int& ix,
                                           float& rely, float& relx, float& rrev) {
    const size_t base = ((size_t)b * Qn + q) * 2;
    const float cy = coord[base + 0];
    const float cx = coord[base + 1];
    const float ey = cell[base + 0];
    const float ex = cell[base + 1];
    const float c_y = cy - ey * 0.5f;
    const float c_x = cx - ex * 0.5f;
    const float cqy = fminf(fmaxf(c_y + EPSf, -1.0f + EPSf), 1.0f - EPSf);
    const float cqx = fminf(fmaxf(c_x + EPSf, -1.0f + EPSf), 1.0f - EPSf);
    float fy = rintf(((cqy + 1.0f) * (float)Hn - 1.0f) * 0.5f);  // round-half-even
    float fx = rintf(((cqx + 1.0f) * (float)Wn - 1.0f) * 0.5f);
    fy = fminf(fmaxf(fy, 0.0f), (float)(Hn - 1));
    fx = fminf(fmaxf(fx, 0.0f), (float)(Wn - 1));
    iy = (int)fy;
    ix = (int)fx;
    const float qcy = -1.0f + 2.0f * fy / (float)Hn;
    const float qcx = -1.0f + 2.0f * fx / (float)Wn;
    rely = (c_y - qcy) * ((float)Hn * 0.5f);
    relx = (c_x - qcx) * ((float)Wn * 0.5f);
    rrev = ey * ((float)Hn * 0.5f);
}

// Kernel 1: the 4 phase-specialized pw matrices. grid=(27,4) block=256.
// Block computes 64 outputs; 4 wave-slices split the HID reduction.
__global__ __launch_bounds__(256) void pw_kernel(
    const float* __restrict__ coord, const float* __restrict__ cell,
    const float* __restrict__ w1, const float* __restrict__ b1,
    const float* __restrict__ w2, const float* __restrict__ b2,
    float* __restrict__ pwbuf) {
    __shared__ float hdd[HIDn];
    __shared__ float part[4 * 64];
    const int p  = blockIdx.y;          // phase 0..3 -> (py,px)
    const int py = p >> 1, px = p & 1;
    const int q  = py * QWn + px;       // representative query, batch 0

    int iy, ix; float rely, relx, rrev;
    coord_math(coord, cell, 0, q, iy, ix, rely, relx, rrev);

    const int tid = threadIdx.x;
    {   // hidden layer: thread j computes hdd[j]
        const int j = tid;
        float h = b1[j] + rely * w1[j] + relx * w1[HIDn + j] + rrev * w1[2 * HIDn + j];
        hdd[j] = fmaxf(h, 0.0f);
    }
    __syncthreads();

    const int tloc  = tid & 63;
    const int slice = tid >> 6;
    const int t     = blockIdx.x * 64 + tloc;   // 0..1727

    float s = 0.0f;
    const int j0 = slice * 64;
    #pragma unroll 16
    for (int jj = 0; jj < 64; ++jj)
        s = fmaf(hdd[j0 + jj], w2[(size_t)(j0 + jj) * OUTn + t], s);
    part[slice * 64 + tloc] = s;
    __syncthreads();

    if (tid < 64) {
        const int tt  = blockIdx.x * 64 + tid;
        float v = b2[tt] + part[tid] + part[64 + tid] + part[128 + tid] + part[192 + tid];
        const int c   = tt / 27;
        const int rem = tt - c * 27;     // tap*3 + o
        pwbuf[c * 112 + p * 28 + rem] = v;
    }
}

// Kernel 2: thread = (LR pixel in 8x8 tile, 16-ch slice); computes all 4 phases
// from shared taps. Channel-inner LDS patch for ds_read_b128 taps; wave-uniform
// float4 weight loads (L1-resident). grid=(8,8,4) block=256.
__global__ __launch_bounds__(256) void metasr_main(
    const float* __restrict__ feat, const float* __restrict__ pw,
    float* __restrict__ out) {
    __shared__ float4 patch4[100 * 17];   // [pix][68 floats]: 64 ch + 4 pad, 27.2 KB
    __shared__ float  part[64 * 49];      // [pix][4 slices * 12 + pad], 12.5 KB

    const int tid = threadIdx.x;
    const int bz  = blockIdx.z;
    const int i0  = blockIdx.y * 8;       // LR tile origin
    const int j0  = blockIdx.x * 8;
    float* patchf = (float*)patch4;

    // ---- stage patch cube, transposed to channel-inner (zero halo) ----
    for (int e = tid; e < Cn * 100; e += 256) {
        const int c  = e / 100;
        const int r  = e - c * 100;       // pix = yy*10+xx
        const int yy = r / 10;
        const int xx = r - yy * 10;
        const int gy = i0 - 1 + yy;
        const int gx = j0 - 1 + xx;
        float v = 0.0f;
        if ((unsigned)gy < (unsigned)Hn && (unsigned)gx < (unsigned)Wn)
            v = feat[(((size_t)bz * Cn + c) << 12) + (gy << 6) + gx];
        patchf[r * 68 + c] = v;
    }
    __syncthreads();

    const int pix   = tid & 63;           // lanes = pixels -> weights wave-uniform
    const int slice = tid >> 6;           // 16 channels per slice
    const int li    = pix >> 3, lj = pix & 7;

    float acc[4][3] = {};
    #pragma unroll
    for (int g = 0; g < 4; ++g) {         // 4-channel groups within slice
        const int gg = (slice << 2) + g;
        float4 v[9];
        #pragma unroll
        for (int ky = 0; ky < 3; ++ky)
            #pragma unroll
            for (int kx = 0; kx < 3; ++kx)
                v[ky * 3 + kx] = patch4[((li + ky) * 10 + lj + kx) * 17 + gg];
        #pragma unroll
        for (int cc = 0; cc < 4; ++cc) {
            float vc[9];
            #pragma unroll
            for (int t = 0; t < 9; ++t)
                vc[t] = cc == 0 ? v[t].x : cc == 1 ? v[t].y : cc == 2 ? v[t].z : v[t].w;
            const int c = (gg << 2) + cc; // wave-uniform channel
            #pragma unroll
            for (int p = 0; p < 4; ++p) {
                const float4* w4 = (const float4*)(pw + c * 112 + p * 28);
                float4 wv[7];
                #pragma unroll
                for (int i = 0; i < 7; ++i) wv[i] = w4[i];
                const float* w = (const float*)wv;
                #pragma unroll
                for (int t = 0; t < 9; ++t)
                    #pragma unroll
                    for (int o = 0; o < 3; ++o)
                        acc[p][o] = fmaf(vc[t], w[t * 3 + o], acc[p][o]);
            }
        }
    }

    #pragma unroll
    for (int p = 0; p < 4; ++p)
        #pragma unroll
        for (int o = 0; o < 3; ++o)
            part[pix * 49 + slice * 12 + p * 3 + o] = acc[p][o];
    __syncthreads();

    {   // epilogue: thread = (pix, phase); sum 4 slices, write 3 outputs
        const int p  = tid >> 6;
        const int py = p >> 1, px = p & 1;
        const int Y  = ((i0 + li) << 1) + py;
        const int X  = ((j0 + lj) << 1) + px;
        float r0 = 0.f, r1 = 0.f, r2 = 0.f;
        #pragma unroll
        for (int s = 0; s < 4; ++s) {
            r0 += part[pix * 49 + s * 12 + p * 3 + 0];
            r1 += part[pix * 49 + s * 12 + p * 3 + 1];
            r2 += part[pix * 49 + s * 12 + p * 3 + 2];
        }
        const size_t oi = ((size_t)bz * Qn + (size_t)Y * QWn + X) * 3;
        out[oi + 0] = r0;
        out[oi + 1] = r1;
        out[oi + 2] = r2;
    }
}

extern "C" void kernel_launch(void* const* d_in, const int* in_sizes, int n_in,
                              void* d_out, int out_size, void* d_ws, size_t ws_size,
                              hipStream_t stream) {
    const float* feat  = (const float*)d_in[0];
    const float* coord = (const float*)d_in[1];
    const float* cell  = (const float*)d_in[2];
    const float* w1    = (const float*)d_in[3];
    const float* b1    = (const float*)d_in[4];
    const float* w2    = (const float*)d_in[5];
    const float* b2    = (const float*)d_in[6];
    float* out = (float*)d_out;
    float* pw  = (float*)d_ws;   // PW_TOTAL floats = 28,672 B scratch

    pw_kernel<<<dim3(27, 4, 1), 256, 0, stream>>>(coord, cell, w1, b1, w2, b2, pw);
    metasr_main<<<dim3(8, 8, 4), 256, 0, stream>>>(feat, pw, out);
}